// Round 1
// baseline (518.541 us; speedup 1.0000x reference)
//
#include <hip/hip_runtime.h>

#define LOG2E 1.44269504088896340736f

constexpr int B  = 128;
constexpr int T  = 2048;
constexpr int Fd = 128;   // input features
constexpr int H  = 8;     // hidden
constexpr int G  = 32;    // 4H gates per direction
constexpr int BT = B * T;

// ---------------------------------------------------------------------------
// Kernel 1: input projection  xz[dir][b*T+t][g] = sum_f x[b][t][f]*W[f][g] + b[g]
// Both directions fused: 64 gate columns (0-31 fw, 32-63 bw).
// Block: 256 threads. Thread = (gate octet gg=tid&7, row quad rg=tid>>3).
// Each block: 256 rows (2 chunks of 128). Grid = BT/256 = 1024.
// ---------------------------------------------------------------------------
__global__ __launch_bounds__(256) void lstm_proj(
    const float* __restrict__ x,
    const float* __restrict__ W_fw, const float* __restrict__ b_fw,
    const float* __restrict__ W_bw, const float* __restrict__ b_bw,
    float* __restrict__ xz)
{
    __shared__ float Wl[Fd * 64];   // [f][64] : gates 0-31 fw, 32-63 bw
    __shared__ float bl[64];

    const int tid = threadIdx.x;
    for (int i = tid; i < Fd * 64; i += 256) {
        int f = i >> 6, g = i & 63;
        Wl[i] = (g < G) ? W_fw[f * G + g] : W_bw[f * G + (g - G)];
    }
    if (tid < 64) bl[tid] = (tid < G) ? b_fw[tid] : b_bw[tid - G];
    __syncthreads();

    const int gg = tid & 7;        // gate octet -> gates g0..g0+7 (one direction)
    const int rg = tid >> 3;       // 0..31 row-quad index within 128-row chunk
    const int g0 = gg * 8;
    const int dir = g0 >> 5;       // 0 fw, 1 bw
    const int gd  = g0 & 31;

    float bq[8];
    #pragma unroll
    for (int j = 0; j < 8; ++j) bq[j] = bl[g0 + j];

    #pragma unroll
    for (int chunk = 0; chunk < 2; ++chunk) {
        const int r0 = blockIdx.x * 256 + chunk * 128 + rg * 4;
        float acc[4][8];
        #pragma unroll
        for (int r = 0; r < 4; ++r)
            #pragma unroll
            for (int j = 0; j < 8; ++j) acc[r][j] = 0.f;

        #pragma unroll 2
        for (int f0 = 0; f0 < Fd; f0 += 4) {
            float4 xv[4];
            #pragma unroll
            for (int r = 0; r < 4; ++r)
                xv[r] = *(const float4*)(x + (r0 + r) * Fd + f0);
            #pragma unroll
            for (int i = 0; i < 4; ++i) {
                float4 w0 = *(const float4*)(Wl + (f0 + i) * 64 + g0);
                float4 w1 = *(const float4*)(Wl + (f0 + i) * 64 + g0 + 4);
                #pragma unroll
                for (int r = 0; r < 4; ++r) {
                    float xf = (i == 0) ? xv[r].x : (i == 1) ? xv[r].y
                             : (i == 2) ? xv[r].z : xv[r].w;
                    acc[r][0] = fmaf(xf, w0.x, acc[r][0]);
                    acc[r][1] = fmaf(xf, w0.y, acc[r][1]);
                    acc[r][2] = fmaf(xf, w0.z, acc[r][2]);
                    acc[r][3] = fmaf(xf, w0.w, acc[r][3]);
                    acc[r][4] = fmaf(xf, w1.x, acc[r][4]);
                    acc[r][5] = fmaf(xf, w1.y, acc[r][5]);
                    acc[r][6] = fmaf(xf, w1.z, acc[r][6]);
                    acc[r][7] = fmaf(xf, w1.w, acc[r][7]);
                }
            }
        }
        #pragma unroll
        for (int r = 0; r < 4; ++r) {
            float4 o0 = make_float4(acc[r][0] + bq[0], acc[r][1] + bq[1],
                                    acc[r][2] + bq[2], acc[r][3] + bq[3]);
            float4 o1 = make_float4(acc[r][4] + bq[4], acc[r][5] + bq[5],
                                    acc[r][6] + bq[6], acc[r][7] + bq[7]);
            float* dst = xz + (dir * BT + r0 + r) * G + gd;
            *(float4*)dst       = o0;
            *(float4*)(dst + 4) = o1;
        }
    }
}

// ---------------------------------------------------------------------------
// Kernel 2: the sequential scan. One wave per batch.
// Lanes 0-31: forward direction, lanes 32-63: backward. Lane (l&31)=g is gate g
// (Keras order: i=0..7, f=8..15, g=16..23, o=24..31). State (h_j,c_j) lives in
// lanes with g<8 (j=g). h rebroadcast each step via 8 shuffles; gate gather via
// 3 shuffles. xz prefetched 8 steps ahead in a statically-indexed reg ring.
// ---------------------------------------------------------------------------
__global__ __launch_bounds__(64) void lstm_scan(
    const float* __restrict__ xz,
    const float* __restrict__ U_fw,
    const float* __restrict__ U_bw,
    float* __restrict__ out)
{
    const int b    = blockIdx.x;
    const int lane = threadIdx.x;
    const int g    = lane & 31;
    const int half = lane >> 5;          // 0 fw, 1 bw
    const int hsrc = lane & 32;          // first lane of this half

    const float* Up = half ? U_bw : U_fw;
    float u[8];
    #pragma unroll
    for (int j = 0; j < 8; ++j) u[j] = Up[j * G + g];   // U[j][g]

    // activation selectors: gates 16..23 are tanh, rest sigmoid.
    const bool  isG = (g >= 16) && (g < 24);
    const float ek  = isG ? (-2.0f * LOG2E) : (-LOG2E);
    const float am  = isG ? 2.0f : 1.0f;
    const float ab  = isG ? -1.0f : 0.0f;

    const int base = (half * BT + b * T) * G + g;
    float* outp = out + (b * T) * (2 * H) + half * H + g;   // + t*16 later

    float h = 0.f, c = 0.f;

    // 8-deep prefetch ring (static indices only)
    float buf[8];
    #pragma unroll
    for (int k = 0; k < 8; ++k) {
        int tt = half ? (T - 1 - k) : k;
        buf[k] = xz[base + tt * G];
    }

    for (int s0 = 0; s0 < T; s0 += 8) {
        #pragma unroll
        for (int k = 0; k < 8; ++k) {
            const int s = s0 + k;
            float z0 = buf[k];

            // prefetch s+8 (clamped; stays in-bounds of this scan's region)
            int sn = s + 8; sn = (sn < T) ? sn : (T - 1);
            int tn = half ? (T - 1 - sn) : sn;
            buf[k] = xz[base + tn * G];

            // z = xz + sum_j U[j][g] * h_j   (h_j broadcast from lane hsrc+j)
            float acc0 = z0, acc1 = 0.f;
            #pragma unroll
            for (int jj = 0; jj < 8; jj += 2) {
                float h0 = __shfl(h, hsrc + jj,     64);
                float h1 = __shfl(h, hsrc + jj + 1, 64);
                acc0 = fmaf(u[jj],     h0, acc0);
                acc1 = fmaf(u[jj + 1], h1, acc1);
            }
            float z = acc0 + acc1;

            // a = sigmoid(z) or tanh(z) = 2*sigmoid(2z)-1, one exp2 + one rcp
            float e = __builtin_amdgcn_exp2f(z * ek);
            float a = fmaf(__builtin_amdgcn_rcpf(1.0f + e), am, ab);

            // lanes j<8: a(self)=i_j; gather f,g,o from lanes j+8, j+16, j+24
            float af = __shfl(a, lane + 8,  64);
            float ag = __shfl(a, lane + 16, 64);
            float ao = __shfl(a, lane + 24, 64);

            c = fmaf(af, c, a * ag);                       // c = f*c + i*g
            float e2 = __builtin_amdgcn_exp2f(c * (-2.0f * LOG2E));
            float th = fmaf(__builtin_amdgcn_rcpf(1.0f + e2), 2.0f, -1.0f);
            h = ao * th;                                   // h = o * tanh(c)

            if (g < H) {
                int tt = half ? (T - 1 - s) : s;
                outp[tt * (2 * H)] = h;
            }
        }
    }
}

// ---------------------------------------------------------------------------
extern "C" void kernel_launch(void* const* d_in, const int* in_sizes, int n_in,
                              void* d_out, int out_size, void* d_ws, size_t ws_size,
                              hipStream_t stream)
{
    const float* x    = (const float*)d_in[0];
    const float* W_fw = (const float*)d_in[1];
    const float* U_fw = (const float*)d_in[2];
    const float* b_fw = (const float*)d_in[3];
    const float* W_bw = (const float*)d_in[4];
    const float* U_bw = (const float*)d_in[5];
    const float* b_bw = (const float*)d_in[6];
    float* out = (float*)d_out;
    float* xz  = (float*)d_ws;   // needs 2*BT*G*4 = 67.1 MB of scratch

    lstm_proj<<<BT / 256, 256, 0, stream>>>(x, W_fw, b_fw, W_bw, b_bw, xz);
    lstm_scan<<<B, 64, 0, stream>>>(xz, U_fw, U_bw, out);
}

// Round 2
// 414.828 us; speedup vs baseline: 1.2500x; 1.2500x over previous
//
#include <hip/hip_runtime.h>

#define LOG2E 1.44269504088896340736f

constexpr int B  = 128;
constexpr int T  = 2048;
constexpr int Fd = 128;   // input features
constexpr int H  = 8;     // hidden
constexpr int BT = B * T;

// xz workspace layout: [scan=(b*2+dir)][t][32] where the 32 "positions" are
// gate-interleaved: pos 2u -> gate u (i/f block, cols 0..15 of U/W),
// pos 2u+1 -> gate 16+u (g/o block). For dir=1 (backward) time is stored
// pre-reversed, so the scan kernel always walks rows forward.

// ---------------------------------------------------------------------------
// Kernel 1: input projection into the permuted layout above.
// 256 threads: rg=tid>>3 picks a 4-row group, gg=tid&7 picks (dir, 8-position
// slice). Two 128-row chunks per block. Grid = BT/256 = 1024.
// ---------------------------------------------------------------------------
__global__ __launch_bounds__(256) void lstm_proj(
    const float* __restrict__ x,
    const float* __restrict__ W_fw, const float* __restrict__ b_fw,
    const float* __restrict__ W_bw, const float* __restrict__ b_bw,
    float* __restrict__ xz)
{
    __shared__ float Wl[Fd * 64];   // [f][64] in permuted (dir,pos) layout
    __shared__ float bl[64];

    const int tid = threadIdx.x;
    for (int i = tid; i < Fd * 64; i += 256) {
        int f = i >> 6, q = i & 63;
        int d = q >> 5, pos = q & 31;
        int u = pos >> 1, ph = pos & 1;
        const float* Wd = d ? W_bw : W_fw;
        Wl[i] = Wd[f * 32 + ph * 16 + u];
    }
    if (tid < 64) {
        int d = tid >> 5, pos = tid & 31, u = pos >> 1, ph = pos & 1;
        const float* bd = d ? b_bw : b_fw;
        bl[tid] = bd[ph * 16 + u];
    }
    __syncthreads();

    const int gg = tid & 7;
    const int rg = tid >> 3;
    const int d  = gg >> 2;          // direction
    const int p0 = (gg & 3) * 8;     // position slice start

    float bq[8];
    #pragma unroll
    for (int j = 0; j < 8; ++j) bq[j] = bl[d * 32 + p0 + j];

    #pragma unroll
    for (int chunk = 0; chunk < 2; ++chunk) {
        const int r0 = blockIdx.x * 256 + chunk * 128 + rg * 4;
        float acc[4][8];
        #pragma unroll
        for (int r = 0; r < 4; ++r)
            #pragma unroll
            for (int j = 0; j < 8; ++j) acc[r][j] = 0.f;

        #pragma unroll 2
        for (int f0 = 0; f0 < Fd; f0 += 4) {
            float4 xv[4];
            #pragma unroll
            for (int r = 0; r < 4; ++r)
                xv[r] = *(const float4*)(x + (size_t)(r0 + r) * Fd + f0);
            #pragma unroll
            for (int i = 0; i < 4; ++i) {
                float4 w0 = *(const float4*)(Wl + (f0 + i) * 64 + d * 32 + p0);
                float4 w1 = *(const float4*)(Wl + (f0 + i) * 64 + d * 32 + p0 + 4);
                #pragma unroll
                for (int r = 0; r < 4; ++r) {
                    float xf = (i == 0) ? xv[r].x : (i == 1) ? xv[r].y
                             : (i == 2) ? xv[r].z : xv[r].w;
                    acc[r][0] = fmaf(xf, w0.x, acc[r][0]);
                    acc[r][1] = fmaf(xf, w0.y, acc[r][1]);
                    acc[r][2] = fmaf(xf, w0.z, acc[r][2]);
                    acc[r][3] = fmaf(xf, w0.w, acc[r][3]);
                    acc[r][4] = fmaf(xf, w1.x, acc[r][4]);
                    acc[r][5] = fmaf(xf, w1.y, acc[r][5]);
                    acc[r][6] = fmaf(xf, w1.z, acc[r][6]);
                    acc[r][7] = fmaf(xf, w1.w, acc[r][7]);
                }
            }
        }
        #pragma unroll
        for (int r = 0; r < 4; ++r) {
            int row = r0 + r;
            int bb  = row >> 11;            // /T
            int t   = row & 2047;           // %T
            int trow = d ? (T - 1 - t) : t;
            float* dst = xz + ((size_t)(bb * 2 + d) * T + trow) * 32 + p0;
            *(float4*)dst = make_float4(acc[r][0] + bq[0], acc[r][1] + bq[1],
                                        acc[r][2] + bq[2], acc[r][3] + bq[3]);
            *(float4*)(dst + 4) = make_float4(acc[r][4] + bq[4], acc[r][5] + bq[5],
                                              acc[r][6] + bq[6], acc[r][7] + bq[7]);
        }
    }
}

// ---------------------------------------------------------------------------
// Kernel 2: the scan. 16 lanes per scan (wave = 4 scans), all cross-lane via
// DPP. Lane rl<8: gates (i_j, g_j); lane rl>=8: gates (f_j, o_j), j=rl&7.
// h_j lives in lane 8+j. Matvec via v_fmac_f32_dpp row_ror:r with per-lane
// coefficient tables (invalid rotation slots = 0), built from a runtime DPP
// probe so no dependence on rotate-direction convention.
// ---------------------------------------------------------------------------

#define FMAC_ROR(ACC, U, R)                                                  \
    asm("v_fmac_f32_dpp %0, %2, %3 row_ror:" #R " row_mask:0xf bank_mask:0xf"\
        : "=v"(ACC) : "0"(ACC), "v"(h), "v"(U))

#define MUL_ROR(DST, U, R)                                                   \
    asm("v_mul_f32_dpp %0, %1, %2 row_ror:" #R " row_mask:0xf bank_mask:0xf" \
        : "=v"(DST) : "v"(h), "v"(U))

__global__ __launch_bounds__(64) void lstm_scan(
    const float* __restrict__ xz,
    const float* __restrict__ U_fw,
    const float* __restrict__ U_bw,
    float* __restrict__ out)
{
    const int lane = threadIdx.x;
    const int rl   = lane & 15;
    const int scan = blockIdx.x * 4 + (lane >> 4);
    const int b    = scan >> 1;
    const int dir  = scan & 1;
    const int j    = rl & 7;

    const float* Up = dir ? U_bw : U_fw;

    // Coefficient tables: uA[r]/uB[r] multiply the h value delivered by
    // row_ror:r. Probe the actual source lane; zero if it isn't an h-lane.
    float uA[16], uB[16];
    {
        int src0 = rl;                      // r = 0: own lane
        uA[0] = (src0 >= 8) ? Up[(src0 - 8) * 32 + rl]      : 0.f;
        uB[0] = (src0 >= 8) ? Up[(src0 - 8) * 32 + rl + 16] : 0.f;
    }
#define PROBE(R) {                                                            \
        int rec = __builtin_amdgcn_update_dpp(0, rl + 1, 0x120 + R, 0xf, 0xf, false); \
        int src = rec - 1;                                                    \
        bool v = (rec > 0) && (src >= 8);                                     \
        uA[R] = v ? Up[(src - 8) * 32 + rl]      : 0.f;                       \
        uB[R] = v ? Up[(src - 8) * 32 + rl + 16] : 0.f; }
    PROBE(1)  PROBE(2)  PROBE(3)  PROBE(4)  PROBE(5)
    PROBE(6)  PROBE(7)  PROBE(8)  PROBE(9)  PROBE(10)
    PROBE(11) PROBE(12) PROBE(13) PROBE(14) PROBE(15)
#undef PROBE

    // B-gate activation: tanh for lanes<8 (g), sigmoid for lanes>=8 (o)
    const bool  isTanh = (rl < 8);
    const float ekB = isTanh ? (-2.0f * LOG2E) : (-LOG2E);
    const float amB = isTanh ? 2.0f : 1.0f;
    const float abB = isTanh ? -1.0f : 0.0f;

    const float* xzp = xz + (size_t)scan * T * 32 + 2 * rl;

    const bool writer = (rl >= 8);
    float* op = out + ((size_t)b * T + (dir ? (T - 1) : 0)) * (2 * H) + dir * H + j;
    const int odelta = dir ? -(2 * H) : (2 * H);

    float h = 0.f, c = 0.f;

    float2 buf[8];
    #pragma unroll
    for (int k = 0; k < 8; ++k)
        buf[k] = *(const float2*)(xzp + (size_t)k * 32);

    for (int s0 = 0; s0 < T; s0 += 8) {
        #pragma unroll
        for (int k = 0; k < 8; ++k) {
            const int s = s0 + k;
            float zA = buf[k].x, zB = buf[k].y;
            int sp = s + 8; sp = (sp < T) ? sp : (T - 1);
            buf[k] = *(const float2*)(xzp + (size_t)sp * 32);

            // z = xz + sum_k U[k][gate] * h_k  -- two chains per gate
            float accA = zA, accB = zB, accA2, accB2;
            MUL_ROR(accA2, uA[1], 1);   MUL_ROR(accB2, uB[1], 1);
            accA = fmaf(h, uA[0], accA);
            accB = fmaf(h, uB[0], accB);
            FMAC_ROR(accA,  uA[2],  2);  FMAC_ROR(accB,  uB[2],  2);
            FMAC_ROR(accA2, uA[3],  3);  FMAC_ROR(accB2, uB[3],  3);
            FMAC_ROR(accA,  uA[4],  4);  FMAC_ROR(accB,  uB[4],  4);
            FMAC_ROR(accA2, uA[5],  5);  FMAC_ROR(accB2, uB[5],  5);
            FMAC_ROR(accA,  uA[6],  6);  FMAC_ROR(accB,  uB[6],  6);
            FMAC_ROR(accA2, uA[7],  7);  FMAC_ROR(accB2, uB[7],  7);
            FMAC_ROR(accA,  uA[8],  8);  FMAC_ROR(accB,  uB[8],  8);
            FMAC_ROR(accA2, uA[9],  9);  FMAC_ROR(accB2, uB[9],  9);
            FMAC_ROR(accA,  uA[10], 10); FMAC_ROR(accB,  uB[10], 10);
            FMAC_ROR(accA2, uA[11], 11); FMAC_ROR(accB2, uB[11], 11);
            FMAC_ROR(accA,  uA[12], 12); FMAC_ROR(accB,  uB[12], 12);
            FMAC_ROR(accA2, uA[13], 13); FMAC_ROR(accB2, uB[13], 13);
            FMAC_ROR(accA,  uA[14], 14); FMAC_ROR(accB,  uB[14], 14);
            FMAC_ROR(accA2, uA[15], 15); FMAC_ROR(accB2, uB[15], 15);
            float zAf = accA + accA2;
            float zBf = accB + accB2;

            // A-gate is always sigmoid (i for rl<8, f for rl>=8)
            float eA = __builtin_amdgcn_exp2f(zAf * (-LOG2E));
            float aA = __builtin_amdgcn_rcpf(1.0f + eA);
            // B-gate: tanh (g) or sigmoid (o)
            float eB = __builtin_amdgcn_exp2f(zBf * ekB);
            float aB = fmaf(__builtin_amdgcn_rcpf(1.0f + eB), amB, abB);

            // p = i*g (meaningful in lanes<8); move to lane j+8. Issue both
            // shift directions with zero-fill; the wrong one contributes 0.
            float p = aA * aB;
            float pp = __int_as_float(__builtin_amdgcn_update_dpp(
                           0, __float_as_int(p), 0x118, 0xf, 0xf, false))   // row_shr:8
                     + __int_as_float(__builtin_amdgcn_update_dpp(
                           0, __float_as_int(p), 0x108, 0xf, 0xf, false));  // row_shl:8

            c = fmaf(aA, c, pp);                 // f*c + i*g   (lanes>=8 valid)
            float e2 = __builtin_amdgcn_exp2f(c * (-2.0f * LOG2E));
            float th = fmaf(__builtin_amdgcn_rcpf(1.0f + e2), 2.0f, -1.0f);
            h = aB * th;                         // o * tanh(c) (lanes>=8 valid)

            if (writer) *op = h;
            op += odelta;
        }
    }
}

// ---------------------------------------------------------------------------
extern "C" void kernel_launch(void* const* d_in, const int* in_sizes, int n_in,
                              void* d_out, int out_size, void* d_ws, size_t ws_size,
                              hipStream_t stream)
{
    const float* x    = (const float*)d_in[0];
    const float* W_fw = (const float*)d_in[1];
    const float* U_fw = (const float*)d_in[2];
    const float* b_fw = (const float*)d_in[3];
    const float* W_bw = (const float*)d_in[4];
    const float* U_bw = (const float*)d_in[5];
    const float* b_bw = (const float*)d_in[6];
    float* out = (float*)d_out;
    float* xz  = (float*)d_ws;   // 2*BT*32*4 = 67.1 MB scratch

    lstm_proj<<<BT / 256, 256, 0, stream>>>(x, W_fw, b_fw, W_bw, b_bw, xz);
    lstm_scan<<<(2 * B) / 4, 64, 0, stream>>>(xz, U_fw, U_bw, out);
}